// Round 6
// baseline (2266.024 us; speedup 1.0000x reference)
//
#include <hip/hip_runtime.h>
#include <cstdint>
#include <cstddef>

// ---------------------------------------------------------------------------
// AdaAttN fused kernel set, fp16 MFMA path.
//   B=4, C=KP=512, N=M=4096.
//   ws layout (fp16): Fb[4][4096][512] | Gb[4][4096][512] | VT[4][1536][4096]
//     VT rows per batch: [0..511]   = Hs (v-hat, fp16)
//                        [512..1023]= fp16(v-hat^2)   (hi)
//                        [1024..1535]= v-hat^2 - hi    (lo)  -- protects e2-mean^2
//
// R9: kill the spill by SHRINKING PER-WAVE STATE, not by fighting the cap.
//   R8 post-mortem: (256,2) budget = 256 regs/thread; 32 acc tiles (128 AGPR)
//   + ~140 arch peak (P frags, 2-deep V pipeline, 24 gather address pairs,
//   2x softmax state) = ~270 > 256 -> ~10 regs rotated through scratch each
//   M-tile = 1.4 GB WRITE_SIZE. QBLK=32 reuse itself was right (won while
//   paying ~700us of scratch BW).
//   * 8 waves x 64 channels (same 32x64 block tile): acc = 16 tiles = 64
//     AGPR/wave. QK: wave w owns logit tile (rowtile w>>2, colgroup w&3) --
//     8 tiles exactly cover 32x64, no duplication. PV: 4 cts x (6 loads ->
//     12 MFMAs). Peak ~195 <= 256 cap at launch_bounds(512,2): no spill,
//     ~60 regs headroom for compiler load pipelining.
//   * Numerics identical to R8 (same tile maxima, same f16 P rounding, same
//     accumulation order) -> absmax expected unchanged.
//   NOTE: every loop touching acc[]/m_run/l_run MUST be fully unrolled --
//   a runtime index demotes the array to scratch (R1/R2 bug).
//   Spill tripwire: WRITE_SIZE >> 40 MB per dispatch.
// ---------------------------------------------------------------------------

typedef _Float16 f16;
typedef _Float16 f16x8 __attribute__((ext_vector_type(8)));
typedef float f32x4 __attribute__((ext_vector_type(4)));

#define LOG2E 1.44269504088896340736f

// ---------------------------------------------------------------------------
// conv_ik: out[b][i][k] = bias[k] + sum_c wm[k][c] * in[b][c][i]   (fp16 out)
// ---------------------------------------------------------------------------
__global__ __launch_bounds__(256, 2) void conv_ik(
    const float* __restrict__ in, const float* __restrict__ wm,
    const float* __restrict__ bias, f16* __restrict__ out) {
  const int i0 = blockIdx.x * 64;
  const int k0 = blockIdx.y * 64;
  const int b = blockIdx.z;
  const int tid = threadIdx.x;
  const int lane = tid & 63;
  const int wv = tid >> 6;
  const int l15 = lane & 15;
  const int quad = lane >> 4;

  __shared__ __align__(16) f16 a_lds[64 * 40];  // [i][c] stride 40 (pad)

  const float* inb = in + (size_t)b * (512 * 4096);

  f32x4 acc[4];
#pragma unroll
  for (int t = 0; t < 4; ++t) acc[t] = f32x4{0.f, 0.f, 0.f, 0.f};

  for (int cs = 0; cs < 512; cs += 32) {
    __syncthreads();
#pragma unroll
    for (int rep = 0; rep < 2; ++rep) {
      int chunk = tid + rep * 256;  // 0..511
      int cc = chunk >> 4;          // 0..31
      int f4 = chunk & 15;          // 0..15
      float4 v = *(const float4*)(inb + (size_t)(cs + cc) * 4096 + i0 + f4 * 4);
      int ib = f4 * 4;
      a_lds[(ib + 0) * 40 + cc] = (f16)v.x;
      a_lds[(ib + 1) * 40 + cc] = (f16)v.y;
      a_lds[(ib + 2) * 40 + cc] = (f16)v.z;
      a_lds[(ib + 3) * 40 + cc] = (f16)v.w;
    }
    __syncthreads();
    f16x8 af = *(const f16x8*)&a_lds[(wv * 16 + l15) * 40 + quad * 8];
#pragma unroll
    for (int ct = 0; ct < 4; ++ct) {
      const float* wp = wm + (size_t)(k0 + ct * 16 + l15) * 512 + cs + quad * 8;
      float4 w0 = *(const float4*)wp;
      float4 w1 = *(const float4*)(wp + 4);
      f16x8 bf;
      bf[0] = (f16)w0.x; bf[1] = (f16)w0.y; bf[2] = (f16)w0.z; bf[3] = (f16)w0.w;
      bf[4] = (f16)w1.x; bf[5] = (f16)w1.y; bf[6] = (f16)w1.z; bf[7] = (f16)w1.w;
      acc[ct] = __builtin_amdgcn_mfma_f32_16x16x32_f16(af, bf, acc[ct], 0, 0, 0);
    }
  }
#pragma unroll
  for (int ct = 0; ct < 4; ++ct) {
    int k = k0 + ct * 16 + l15;
    float bv = bias[k];
#pragma unroll
    for (int r = 0; r < 4; ++r) {
      int i = i0 + wv * 16 + quad * 4 + r;
      out[((size_t)b * 4096 + i) * 512 + k] = (f16)(acc[ct][r] + bv);
    }
  }
}

// ---------------------------------------------------------------------------
// conv_vt: val = bias[k] + sum_c wm[k][c] * in[b][c][i]
//   VT[b][k][i]=fp16(val); VT[b][512+k][i]=hi(val^2); VT[b][1024+k][i]=lo
// ---------------------------------------------------------------------------
__global__ __launch_bounds__(256, 2) void conv_vt(
    const float* __restrict__ in, const float* __restrict__ wm,
    const float* __restrict__ bias, f16* __restrict__ vt) {
  const int i0 = blockIdx.x * 64;
  const int k0 = blockIdx.y * 64;
  const int b = blockIdx.z;
  const int tid = threadIdx.x;
  const int lane = tid & 63;
  const int wv = tid >> 6;
  const int l15 = lane & 15;
  const int quad = lane >> 4;

  __shared__ __align__(16) f16 b_lds[64 * 40];  // [i][c] stride 40

  const float* inb = in + (size_t)b * (512 * 4096);

  f32x4 acc[4];
#pragma unroll
  for (int t = 0; t < 4; ++t) acc[t] = f32x4{0.f, 0.f, 0.f, 0.f};

  for (int cs = 0; cs < 512; cs += 32) {
    __syncthreads();
#pragma unroll
    for (int rep = 0; rep < 2; ++rep) {
      int chunk = tid + rep * 256;
      int cc = chunk >> 4;
      int f4 = chunk & 15;
      float4 v = *(const float4*)(inb + (size_t)(cs + cc) * 4096 + i0 + f4 * 4);
      int ib = f4 * 4;
      b_lds[(ib + 0) * 40 + cc] = (f16)v.x;
      b_lds[(ib + 1) * 40 + cc] = (f16)v.y;
      b_lds[(ib + 2) * 40 + cc] = (f16)v.z;
      b_lds[(ib + 3) * 40 + cc] = (f16)v.w;
    }
    __syncthreads();
    const float* wp = wm + (size_t)(k0 + wv * 16 + l15) * 512 + cs + quad * 8;
    float4 w0 = *(const float4*)wp;
    float4 w1 = *(const float4*)(wp + 4);
    f16x8 af;
    af[0] = (f16)w0.x; af[1] = (f16)w0.y; af[2] = (f16)w0.z; af[3] = (f16)w0.w;
    af[4] = (f16)w1.x; af[5] = (f16)w1.y; af[6] = (f16)w1.z; af[7] = (f16)w1.w;
#pragma unroll
    for (int ct = 0; ct < 4; ++ct) {
      f16x8 bfr = *(const f16x8*)&b_lds[(ct * 16 + l15) * 40 + quad * 8];
      acc[ct] = __builtin_amdgcn_mfma_f32_16x16x32_f16(af, bfr, acc[ct], 0, 0, 0);
    }
  }
  f16* vtb = vt + (size_t)b * 1536 * 4096;
#pragma unroll
  for (int ct = 0; ct < 4; ++ct) {
    int i = i0 + ct * 16 + l15;
#pragma unroll
    for (int r = 0; r < 4; ++r) {
      int k = k0 + wv * 16 + quad * 4 + r;
      float val = acc[ct][r] + bias[k];
      f16 vh = (f16)val;
      float vf = (float)vh;
      float sq = vf * vf;
      f16 sqh = (f16)sq;
      f16 sql = (f16)(sq - (float)sqh);
      vtb[(size_t)k * 4096 + i] = vh;
      vtb[(size_t)(512 + k) * 4096 + i] = sqh;
      vtb[(size_t)(1024 + k) * 4096 + i] = sql;
    }
  }
}

// ---------------------------------------------------------------------------
// adaattn_flash: per block = 32 Q-rows of one batch; 8 waves; M-tiles of 64.
//   QK: wave w computes logit tile (rowtile rt=w>>2, colgroup cg=w&3) --
//       8 tiles exactly cover 32 rows x 64 cols.
//   PV: wave w owns V channels [w*64, w*64+64): acc = 2 rowtiles x 4
//       ch-tiles x {mean, e2} = 16 tiles = 64 AGPR. e2 hi AND lo accumulate
//       into the same accE (MFMA C is in/out).
//   Epilogue wave-local. LDS: p_lds[32][72] + smax/ssum[2][4][16] = 5632 B.
//   launch_bounds(512,2): 256 regs/thread cap, demand ~195 -> no spill.
//   Grid 128x4 = 512 blocks of 512 threads.
// ---------------------------------------------------------------------------
__global__ __launch_bounds__(512, 2) void adaattn_flash(
    const f16* __restrict__ Fb, const f16* __restrict__ Gb,
    const f16* __restrict__ VT, const float* __restrict__ cx,
    float* __restrict__ out) {
  const int n0 = blockIdx.x * 32;
  const int b = blockIdx.y;
  const int tid = threadIdx.x;
  const int lane = tid & 63;
  const int wv = tid >> 6;     // 0..7
  const int l15 = lane & 15;
  const int quad = lane >> 4;
  const int rt = wv >> 2;      // QK rowtile (0/1)
  const int cg = wv & 3;       // QK colgroup (16 cols)

  __shared__ __align__(16) f16 p_lds[32 * 72];  // [qrow 0..31][mcol] stride 72
  __shared__ float smax[128];                   // [rt][cg][row16]
  __shared__ float ssum[128];

  // F A-fragment base for this wave's QK rowtile (L1-hot)
  const f16* fp = Fb + ((size_t)b * 4096 + n0 + rt * 16 + l15) * 512 + quad * 8;
  // G B-fragment base for this wave's 16 logit columns (direct global)
  const f16* gq0 = Gb + ((size_t)b * 4096 + cg * 16 + l15) * 512 + quad * 8;
  // V row-group bases: wave's own 64-channel slice of mean / e2hi / e2lo
  const f16* vb0 = VT + ((size_t)b * 1536 + (size_t)wv * 64 + l15) * 4096;
  const f16* vb1 = vb0 + (size_t)512 * 4096;
  const f16* vb2 = vb1 + (size_t)512 * 4096;

  f32x4 accM0[4], accE0[4], accM1[4], accE1[4];
#pragma unroll
  for (int t = 0; t < 4; ++t) {
    accM0[t] = f32x4{0.f, 0.f, 0.f, 0.f};
    accE0[t] = f32x4{0.f, 0.f, 0.f, 0.f};
    accM1[t] = f32x4{0.f, 0.f, 0.f, 0.f};
    accE1[t] = f32x4{0.f, 0.f, 0.f, 0.f};
  }
  float m_run0[4] = {-1e30f, -1e30f, -1e30f, -1e30f};
  float m_run1[4] = {-1e30f, -1e30f, -1e30f, -1e30f};
  float l_run0[4] = {0.f, 0.f, 0.f, 0.f};
  float l_run1[4] = {0.f, 0.f, 0.f, 0.f};

  for (int m0 = 0; m0 < 4096; m0 += 64) {
    // --- QK: one 16x16 logit tile per wave, K=512 --------------------------
    f32x4 lg = f32x4{0.f, 0.f, 0.f, 0.f};
    {
      const f16* gq = gq0 + (size_t)m0 * 512;
#pragma unroll 8
      for (int ks = 0; ks < 16; ++ks) {
        f16x8 gf = *(const f16x8*)(gq + ks * 32);
        f16x8 ff = *(const f16x8*)(fp + ks * 32);
        lg = __builtin_amdgcn_mfma_f32_16x16x32_f16(ff, gf, lg, 0, 0, 0);
      }
    }

    // --- wave-local row max over this wave's 16 cols (butterfly) -----------
#pragma unroll
    for (int r = 0; r < 4; ++r) {
      float v = lg[r];
      v = fmaxf(v, __shfl_xor(v, 1));
      v = fmaxf(v, __shfl_xor(v, 2));
      v = fmaxf(v, __shfl_xor(v, 4));
      v = fmaxf(v, __shfl_xor(v, 8));
      if (l15 == 0) smax[rt * 64 + cg * 16 + quad * 4 + r] = v;
    }
    __syncthreads();  // bar1: smax complete; fences prev-iter p_lds reads

    float alpha0[4], alpha1[4], ts[4];
#pragma unroll
    for (int r = 0; r < 4; ++r) {
      int row = quad * 4 + r;
      // running max for BOTH rowtiles (needed to rescale this wave's acc)
      float mt0 = fmaxf(fmaxf(smax[row], smax[16 + row]),
                        fmaxf(smax[32 + row], smax[48 + row]));
      float mt1 = fmaxf(fmaxf(smax[64 + row], smax[80 + row]),
                        fmaxf(smax[96 + row], smax[112 + row]));
      float mn0 = fmaxf(m_run0[r], mt0);
      float mn1 = fmaxf(m_run1[r], mt1);
      alpha0[r] = exp2f((m_run0[r] - mn0) * LOG2E);
      alpha1[r] = exp2f((m_run1[r] - mn1) * LOG2E);
      m_run0[r] = mn0;
      m_run1[r] = mn1;
      // P for this wave's OWN logit tile (rt is wave-uniform)
      float mn_my = rt ? mn1 : mn0;
      float p = exp2f((lg[r] - mn_my) * LOG2E);
      f16 ph = (f16)p;  // round first so weights & sums agree exactly
      p = (float)ph;
      p_lds[(rt * 16 + row) * 72 + cg * 16 + l15] = ph;
      float s = p;
      s += __shfl_xor(s, 1);
      s += __shfl_xor(s, 2);
      s += __shfl_xor(s, 4);
      s += __shfl_xor(s, 8);
      ts[r] = s;
    }
    if (l15 == 0) {
#pragma unroll
      for (int r = 0; r < 4; ++r) ssum[rt * 64 + cg * 16 + quad * 4 + r] = ts[r];
    }
    // rescale accumulators by alpha (per-row); skip when all alpha == 1
    if (__any(alpha0[0] != 1.f || alpha0[1] != 1.f ||
              alpha0[2] != 1.f || alpha0[3] != 1.f ||
              alpha1[0] != 1.f || alpha1[1] != 1.f ||
              alpha1[2] != 1.f || alpha1[3] != 1.f)) {
#pragma unroll
      for (int t = 0; t < 4; ++t) {
#pragma unroll
        for (int r = 0; r < 4; ++r) {
          accM0[t][r] *= alpha0[r];
          accE0[t][r] *= alpha0[r];
          accM1[t][r] *= alpha1[r];
          accE1[t][r] *= alpha1[r];
        }
      }
    }
    __syncthreads();  // bar2: p_lds + ssum complete

#pragma unroll
    for (int r = 0; r < 4; ++r) {
      int row = quad * 4 + r;
      l_run0[r] = l_run0[r] * alpha0[r] +
                  (ssum[row] + ssum[16 + row] + ssum[32 + row] + ssum[48 + row]);
      l_run1[r] = l_run1[r] * alpha1[r] +
                  (ssum[64 + row] + ssum[80 + row] + ssum[96 + row] + ssum[112 + row]);
    }

    // --- PV: A = P (LDS), B = VT direct global; per-ct loads ---------------
    f16x8 pf00 = *(const f16x8*)&p_lds[l15 * 72 + quad * 8];
    f16x8 pf01 = *(const f16x8*)&p_lds[l15 * 72 + 32 + quad * 8];
    f16x8 pf10 = *(const f16x8*)&p_lds[(16 + l15) * 72 + quad * 8];
    f16x8 pf11 = *(const f16x8*)&p_lds[(16 + l15) * 72 + 32 + quad * 8];
    const f16* vpm = vb0 + m0 + quad * 8;
    const f16* vph = vb1 + m0 + quad * 8;
    const f16* vpl = vb2 + m0 + quad * 8;
#pragma unroll
    for (int ct = 0; ct < 4; ++ct) {
      const size_t o = (size_t)ct * (16 * 4096);
      f16x8 vm0 = *(const f16x8*)(vpm + o);
      f16x8 vm1 = *(const f16x8*)(vpm + o + 32);
      f16x8 vh0 = *(const f16x8*)(vph + o);
      f16x8 vh1 = *(const f16x8*)(vph + o + 32);
      f16x8 vl0 = *(const f16x8*)(vpl + o);
      f16x8 vl1 = *(const f16x8*)(vpl + o + 32);
      accM0[ct] = __builtin_amdgcn_mfma_f32_16x16x32_f16(pf00, vm0, accM0[ct], 0, 0, 0);
      accM0[ct] = __builtin_amdgcn_mfma_f32_16x16x32_f16(pf01, vm1, accM0[ct], 0, 0, 0);
      accM1[ct] = __builtin_amdgcn_mfma_f32_16x16x32_f16(pf10, vm0, accM1[ct], 0, 0, 0);
      accM1[ct] = __builtin_amdgcn_mfma_f32_16x16x32_f16(pf11, vm1, accM1[ct], 0, 0, 0);
      accE0[ct] = __builtin_amdgcn_mfma_f32_16x16x32_f16(pf00, vh0, accE0[ct], 0, 0, 0);
      accE0[ct] = __builtin_amdgcn_mfma_f32_16x16x32_f16(pf01, vh1, accE0[ct], 0, 0, 0);
      accE1[ct] = __builtin_amdgcn_mfma_f32_16x16x32_f16(pf10, vh0, accE1[ct], 0, 0, 0);
      accE1[ct] = __builtin_amdgcn_mfma_f32_16x16x32_f16(pf11, vh1, accE1[ct], 0, 0, 0);
      accE0[ct] = __builtin_amdgcn_mfma_f32_16x16x32_f16(pf00, vl0, accE0[ct], 0, 0, 0);
      accE0[ct] = __builtin_amdgcn_mfma_f32_16x16x32_f16(pf01, vl1, accE0[ct], 0, 0, 0);
      accE1[ct] = __builtin_amdgcn_mfma_f32_16x16x32_f16(pf10, vl0, accE1[ct], 0, 0, 0);
      accE1[ct] = __builtin_amdgcn_mfma_f32_16x16x32_f16(pf11, vl1, accE1[ct], 0, 0, 0);
    }
  }

  // ---------------- epilogue (wave-local, no LDS, no barriers) ------------
  float inv0[4], inv1[4];
#pragma unroll
  for (int r = 0; r < 4; ++r) {
    inv0[r] = 1.0f / l_run0[r];
    inv1[r] = 1.0f / l_run1[r];
  }

  const size_t base = ((size_t)b * 512) * 4096 + n0 + quad * 4;
#pragma unroll
  for (int ct = 0; ct < 4; ++ct) {
    int c = wv * 64 + ct * 16 + l15;
    size_t off0 = base + (size_t)c * 4096;
    size_t off1 = off0 + 16;
    f32x4 cxv0 = *(const f32x4*)(cx + off0);
    f32x4 cxv1 = *(const f32x4*)(cx + off1);
    f32x4 o0, o1;
#pragma unroll
    for (int r = 0; r < 4; ++r) {
      float m = accM0[ct][r] * inv0[r];
      float e2 = accE0[ct][r] * inv0[r];
      float sd = sqrtf(fmaxf(e2 - m * m, 0.f));
      o0[r] = sd * cxv0[r] + m;
      float m1 = accM1[ct][r] * inv1[r];
      float e21 = accE1[ct][r] * inv1[r];
      float sd1 = sqrtf(fmaxf(e21 - m1 * m1, 0.f));
      o1[r] = sd1 * cxv1[r] + m1;
    }
    *(f32x4*)(out + off0) = o0;
    *(f32x4*)(out + off1) = o1;
  }
}

// ---------------------------------------------------------------------------
extern "C" void kernel_launch(void* const* d_in, const int* in_sizes, int n_in,
                              void* d_out, int out_size, void* d_ws, size_t ws_size,
                              hipStream_t stream) {
  (void)in_sizes; (void)n_in; (void)out_size;
  const float* c_x  = (const float*)d_in[0];
  const float* s_x  = (const float*)d_in[1];
  const float* c_1x = (const float*)d_in[2];
  const float* s_1x = (const float*)d_in[3];
  const float* f_w  = (const float*)d_in[4];
  const float* f_b  = (const float*)d_in[5];
  const float* g_w  = (const float*)d_in[6];
  const float* g_b  = (const float*)d_in[7];
  const float* h_w  = (const float*)d_in[8];
  const float* h_b  = (const float*)d_in[9];
  float* out = (float*)d_out;

  const size_t fe = (size_t)4 * 4096 * 512;  // elements per F/G buffer
  f16* Fb = (f16*)d_ws;
  f16* Gb = Fb + fe;
  f16* VT = Gb + fe;
  const size_t need = fe * 2 * sizeof(f16) * 2 + (size_t)4 * 1536 * 4096 * sizeof(f16);
  if (ws_size < need) return;  // 80 MiB required; fail loudly (output stays poisoned)

  dim3 gP(64, 8, 4);
  conv_ik<<<gP, dim3(256), 0, stream>>>(c_1x, f_w, f_b, Fb);
  conv_ik<<<gP, dim3(256), 0, stream>>>(s_1x, g_w, g_b, Gb);
  conv_vt<<<gP, dim3(256), 0, stream>>>(s_x, h_w, h_b, VT);
  adaattn_flash<<<dim3(128, 4), dim3(512), 0, stream>>>(Fb, Gb, VT, c_x, out);
}

// Round 7
// 2263.229 us; speedup vs baseline: 1.0012x; 1.0012x over previous
//
#include <hip/hip_runtime.h>
#include <cstdint>
#include <cstddef>

// ---------------------------------------------------------------------------
// AdaAttN fused kernel set, fp16 MFMA path.
//   B=4, C=KP=512, N=M=4096.
//   ws layout (fp16): Fb[4][4096][512] | Gb[4][4096][512] | VT[4][1536][4096]
//     VT rows per batch: [0..511]   = Hs (v-hat, fp16)
//                        [512..1023]= fp16(v-hat^2)   (hi)
//                        [1024..1535]= v-hat^2 - hi    (lo)  -- protects e2-mean^2
//
// R10: XCD-batch-partitioned block swizzle (single change vs R9).
//   R9 post-mortem: spill fixed (WRITE 33MB, VGPR 92+64) yet 1872us. Latency
//   math can't produce 1872us; an L3-BW ceiling of ~5-7 TB/s on the V+G
//   re-read stream fits R5/R8/R9 within ~20%: every block re-reads its
//   batch's 12MB VT + ~8MB G; per-XCD working set (4 batches ~80MB) >> 4MB
//   L2 -> all misses go to Infinity Cache; 512 blk x 20MB = 10GB / 1872us
//   = 5.5 TB/s == the observed ceiling.
//   * Flatten grid to 1D(512); with round-robin wgid->XCD (m09: xcd=wg&7):
//       xcd = wg&7; b = xcd>>1; n0 = ((xcd&1)*64 + wg>>3) * 32
//     -> each XCD serves ONE batch (2 XCDs/batch), consecutive slots on the
//     same XCD. 32 co-resident blocks/XCD stream the same 256KB/iter V+G
//     window in lockstep -> L2-resident (15-iter skew tolerance), L3 traffic
//     10GB -> ~0.3GB. Failure mode benign: wrong XCD-mapping assumption ==
//     just a different valid (b,n0) permutation, perf unchanged.
//   Kept from R9: 8 waves x 64ch (64 AGPR acc), QK tile/wave, merged e2
//   hi+lo acc, wave-local epilogue, per-ct PV loads, ~5.6KB LDS,
//   launch_bounds(512,2).
//   NOTE: every loop touching acc[]/m_run/l_run MUST be fully unrolled --
//   a runtime index demotes the array to scratch (R1/R2 bug).
//   Spill tripwire: WRITE_SIZE >> 40 MB per dispatch.
// ---------------------------------------------------------------------------

typedef _Float16 f16;
typedef _Float16 f16x8 __attribute__((ext_vector_type(8)));
typedef float f32x4 __attribute__((ext_vector_type(4)));

#define LOG2E 1.44269504088896340736f

// ---------------------------------------------------------------------------
// conv_ik: out[b][i][k] = bias[k] + sum_c wm[k][c] * in[b][c][i]   (fp16 out)
// ---------------------------------------------------------------------------
__global__ __launch_bounds__(256, 2) void conv_ik(
    const float* __restrict__ in, const float* __restrict__ wm,
    const float* __restrict__ bias, f16* __restrict__ out) {
  const int i0 = blockIdx.x * 64;
  const int k0 = blockIdx.y * 64;
  const int b = blockIdx.z;
  const int tid = threadIdx.x;
  const int lane = tid & 63;
  const int wv = tid >> 6;
  const int l15 = lane & 15;
  const int quad = lane >> 4;

  __shared__ __align__(16) f16 a_lds[64 * 40];  // [i][c] stride 40 (pad)

  const float* inb = in + (size_t)b * (512 * 4096);

  f32x4 acc[4];
#pragma unroll
  for (int t = 0; t < 4; ++t) acc[t] = f32x4{0.f, 0.f, 0.f, 0.f};

  for (int cs = 0; cs < 512; cs += 32) {
    __syncthreads();
#pragma unroll
    for (int rep = 0; rep < 2; ++rep) {
      int chunk = tid + rep * 256;  // 0..511
      int cc = chunk >> 4;          // 0..31
      int f4 = chunk & 15;          // 0..15
      float4 v = *(const float4*)(inb + (size_t)(cs + cc) * 4096 + i0 + f4 * 4);
      int ib = f4 * 4;
      a_lds[(ib + 0) * 40 + cc] = (f16)v.x;
      a_lds[(ib + 1) * 40 + cc] = (f16)v.y;
      a_lds[(ib + 2) * 40 + cc] = (f16)v.z;
      a_lds[(ib + 3) * 40 + cc] = (f16)v.w;
    }
    __syncthreads();
    f16x8 af = *(const f16x8*)&a_lds[(wv * 16 + l15) * 40 + quad * 8];
#pragma unroll
    for (int ct = 0; ct < 4; ++ct) {
      const float* wp = wm + (size_t)(k0 + ct * 16 + l15) * 512 + cs + quad * 8;
      float4 w0 = *(const float4*)wp;
      float4 w1 = *(const float4*)(wp + 4);
      f16x8 bf;
      bf[0] = (f16)w0.x; bf[1] = (f16)w0.y; bf[2] = (f16)w0.z; bf[3] = (f16)w0.w;
      bf[4] = (f16)w1.x; bf[5] = (f16)w1.y; bf[6] = (f16)w1.z; bf[7] = (f16)w1.w;
      acc[ct] = __builtin_amdgcn_mfma_f32_16x16x32_f16(af, bf, acc[ct], 0, 0, 0);
    }
  }
#pragma unroll
  for (int ct = 0; ct < 4; ++ct) {
    int k = k0 + ct * 16 + l15;
    float bv = bias[k];
#pragma unroll
    for (int r = 0; r < 4; ++r) {
      int i = i0 + wv * 16 + quad * 4 + r;
      out[((size_t)b * 4096 + i) * 512 + k] = (f16)(acc[ct][r] + bv);
    }
  }
}

// ---------------------------------------------------------------------------
// conv_vt: val = bias[k] + sum_c wm[k][c] * in[b][c][i]
//   VT[b][k][i]=fp16(val); VT[b][512+k][i]=hi(val^2); VT[b][1024+k][i]=lo
// ---------------------------------------------------------------------------
__global__ __launch_bounds__(256, 2) void conv_vt(
    const float* __restrict__ in, const float* __restrict__ wm,
    const float* __restrict__ bias, f16* __restrict__ vt) {
  const int i0 = blockIdx.x * 64;
  const int k0 = blockIdx.y * 64;
  const int b = blockIdx.z;
  const int tid = threadIdx.x;
  const int lane = tid & 63;
  const int wv = tid >> 6;
  const int l15 = lane & 15;
  const int quad = lane >> 4;

  __shared__ __align__(16) f16 b_lds[64 * 40];  // [i][c] stride 40

  const float* inb = in + (size_t)b * (512 * 4096);

  f32x4 acc[4];
#pragma unroll
  for (int t = 0; t < 4; ++t) acc[t] = f32x4{0.f, 0.f, 0.f, 0.f};

  for (int cs = 0; cs < 512; cs += 32) {
    __syncthreads();
#pragma unroll
    for (int rep = 0; rep < 2; ++rep) {
      int chunk = tid + rep * 256;
      int cc = chunk >> 4;
      int f4 = chunk & 15;
      float4 v = *(const float4*)(inb + (size_t)(cs + cc) * 4096 + i0 + f4 * 4);
      int ib = f4 * 4;
      b_lds[(ib + 0) * 40 + cc] = (f16)v.x;
      b_lds[(ib + 1) * 40 + cc] = (f16)v.y;
      b_lds[(ib + 2) * 40 + cc] = (f16)v.z;
      b_lds[(ib + 3) * 40 + cc] = (f16)v.w;
    }
    __syncthreads();
    const float* wp = wm + (size_t)(k0 + wv * 16 + l15) * 512 + cs + quad * 8;
    float4 w0 = *(const float4*)wp;
    float4 w1 = *(const float4*)(wp + 4);
    f16x8 af;
    af[0] = (f16)w0.x; af[1] = (f16)w0.y; af[2] = (f16)w0.z; af[3] = (f16)w0.w;
    af[4] = (f16)w1.x; af[5] = (f16)w1.y; af[6] = (f16)w1.z; af[7] = (f16)w1.w;
#pragma unroll
    for (int ct = 0; ct < 4; ++ct) {
      f16x8 bfr = *(const f16x8*)&b_lds[(ct * 16 + l15) * 40 + quad * 8];
      acc[ct] = __builtin_amdgcn_mfma_f32_16x16x32_f16(af, bfr, acc[ct], 0, 0, 0);
    }
  }
  f16* vtb = vt + (size_t)b * 1536 * 4096;
#pragma unroll
  for (int ct = 0; ct < 4; ++ct) {
    int i = i0 + ct * 16 + l15;
#pragma unroll
    for (int r = 0; r < 4; ++r) {
      int k = k0 + wv * 16 + quad * 4 + r;
      float val = acc[ct][r] + bias[k];
      f16 vh = (f16)val;
      float vf = (float)vh;
      float sq = vf * vf;
      f16 sqh = (f16)sq;
      f16 sql = (f16)(sq - (float)sqh);
      vtb[(size_t)k * 4096 + i] = vh;
      vtb[(size_t)(512 + k) * 4096 + i] = sqh;
      vtb[(size_t)(1024 + k) * 4096 + i] = sql;
    }
  }
}

// ---------------------------------------------------------------------------
// adaattn_flash: per block = 32 Q-rows of one batch; 8 waves; M-tiles of 64.
//   Grid is FLAT 512 blocks; (batch, n0) derived so each XCD serves one
//   batch and consecutive n0-slots share an XCD (L2-resident V+G window).
//   QK: wave w computes logit tile (rowtile rt=w>>2, colgroup cg=w&3).
//   PV: wave w owns V channels [w*64, w*64+64): acc = 2 rowtiles x 4
//       ch-tiles x {mean, e2} = 16 tiles = 64 AGPR. e2 hi AND lo accumulate
//       into the same accE (MFMA C is in/out).
//   Epilogue wave-local. LDS ~5.6KB. launch_bounds(512,2): no spill (R9).
// ---------------------------------------------------------------------------
__global__ __launch_bounds__(512, 2) void adaattn_flash(
    const f16* __restrict__ Fb, const f16* __restrict__ Gb,
    const f16* __restrict__ VT, const float* __restrict__ cx,
    float* __restrict__ out) {
  // --- XCD-batch swizzle: round-robin wgid->XCD (xcd = wg & 7, m09) --------
  const int wg = blockIdx.x;          // 0..511
  const int xcd = wg & 7;             // presumed XCD id
  const int b = xcd >> 1;             // 2 XCDs per batch
  const int n0 = (((xcd & 1) << 6) + (wg >> 3)) * 32;  // bijective: 128 slots/batch

  const int tid = threadIdx.x;
  const int lane = tid & 63;
  const int wv = tid >> 6;     // 0..7
  const int l15 = lane & 15;
  const int quad = lane >> 4;
  const int rt = wv >> 2;      // QK rowtile (0/1)
  const int cg = wv & 3;       // QK colgroup (16 cols)

  __shared__ __align__(16) f16 p_lds[32 * 72];  // [qrow 0..31][mcol] stride 72
  __shared__ float smax[128];                   // [rt][cg][row16]
  __shared__ float ssum[128];

  // F A-fragment base for this wave's QK rowtile (L1-hot)
  const f16* fp = Fb + ((size_t)b * 4096 + n0 + rt * 16 + l15) * 512 + quad * 8;
  // G B-fragment base for this wave's 16 logit columns (direct global)
  const f16* gq0 = Gb + ((size_t)b * 4096 + cg * 16 + l15) * 512 + quad * 8;
  // V row-group bases: wave's own 64-channel slice of mean / e2hi / e2lo
  const f16* vb0 = VT + ((size_t)b * 1536 + (size_t)wv * 64 + l15) * 4096;
  const f16* vb1 = vb0 + (size_t)512 * 4096;
  const f16* vb2 = vb1 + (size_t)512 * 4096;

  f32x4 accM0[4], accE0[4], accM1[4], accE1[4];
#pragma unroll
  for (int t = 0; t < 4; ++t) {
    accM0[t] = f32x4{0.f, 0.f, 0.f, 0.f};
    accE0[t] = f32x4{0.f, 0.f, 0.f, 0.f};
    accM1[t] = f32x4{0.f, 0.f, 0.f, 0.f};
    accE1[t] = f32x4{0.f, 0.f, 0.f, 0.f};
  }
  float m_run0[4] = {-1e30f, -1e30f, -1e30f, -1e30f};
  float m_run1[4] = {-1e30f, -1e30f, -1e30f, -1e30f};
  float l_run0[4] = {0.f, 0.f, 0.f, 0.f};
  float l_run1[4] = {0.f, 0.f, 0.f, 0.f};

  for (int m0 = 0; m0 < 4096; m0 += 64) {
    // --- QK: one 16x16 logit tile per wave, K=512 --------------------------
    f32x4 lg = f32x4{0.f, 0.f, 0.f, 0.f};
    {
      const f16* gq = gq0 + (size_t)m0 * 512;
#pragma unroll 8
      for (int ks = 0; ks < 16; ++ks) {
        f16x8 gf = *(const f16x8*)(gq + ks * 32);
        f16x8 ff = *(const f16x8*)(fp + ks * 32);
        lg = __builtin_amdgcn_mfma_f32_16x16x32_f16(ff, gf, lg, 0, 0, 0);
      }
    }

    // --- wave-local row max over this wave's 16 cols (butterfly) -----------
#pragma unroll
    for (int r = 0; r < 4; ++r) {
      float v = lg[r];
      v = fmaxf(v, __shfl_xor(v, 1));
      v = fmaxf(v, __shfl_xor(v, 2));
      v = fmaxf(v, __shfl_xor(v, 4));
      v = fmaxf(v, __shfl_xor(v, 8));
      if (l15 == 0) smax[rt * 64 + cg * 16 + quad * 4 + r] = v;
    }
    __syncthreads();  // bar1: smax complete; fences prev-iter p_lds reads

    float alpha0[4], alpha1[4], ts[4];
#pragma unroll
    for (int r = 0; r < 4; ++r) {
      int row = quad * 4 + r;
      // running max for BOTH rowtiles (needed to rescale this wave's acc)
      float mt0 = fmaxf(fmaxf(smax[row], smax[16 + row]),
                        fmaxf(smax[32 + row], smax[48 + row]));
      float mt1 = fmaxf(fmaxf(smax[64 + row], smax[80 + row]),
                        fmaxf(smax[96 + row], smax[112 + row]));
      float mn0 = fmaxf(m_run0[r], mt0);
      float mn1 = fmaxf(m_run1[r], mt1);
      alpha0[r] = exp2f((m_run0[r] - mn0) * LOG2E);
      alpha1[r] = exp2f((m_run1[r] - mn1) * LOG2E);
      m_run0[r] = mn0;
      m_run1[r] = mn1;
      // P for this wave's OWN logit tile (rt is wave-uniform)
      float mn_my = rt ? mn1 : mn0;
      float p = exp2f((lg[r] - mn_my) * LOG2E);
      f16 ph = (f16)p;  // round first so weights & sums agree exactly
      p = (float)ph;
      p_lds[(rt * 16 + row) * 72 + cg * 16 + l15] = ph;
      float s = p;
      s += __shfl_xor(s, 1);
      s += __shfl_xor(s, 2);
      s += __shfl_xor(s, 4);
      s += __shfl_xor(s, 8);
      ts[r] = s;
    }
    if (l15 == 0) {
#pragma unroll
      for (int r = 0; r < 4; ++r) ssum[rt * 64 + cg * 16 + quad * 4 + r] = ts[r];
    }
    // rescale accumulators by alpha (per-row); skip when all alpha == 1
    if (__any(alpha0[0] != 1.f || alpha0[1] != 1.f ||
              alpha0[2] != 1.f || alpha0[3] != 1.f ||
              alpha1[0] != 1.f || alpha1[1] != 1.f ||
              alpha1[2] != 1.f || alpha1[3] != 1.f)) {
#pragma unroll
      for (int t = 0; t < 4; ++t) {
#pragma unroll
        for (int r = 0; r < 4; ++r) {
          accM0[t][r] *= alpha0[r];
          accE0[t][r] *= alpha0[r];
          accM1[t][r] *= alpha1[r];
          accE1[t][r] *= alpha1[r];
        }
      }
    }
    __syncthreads();  // bar2: p_lds + ssum complete

#pragma unroll
    for (int r = 0; r < 4; ++r) {
      int row = quad * 4 + r;
      l_run0[r] = l_run0[r] * alpha0[r] +
                  (ssum[row] + ssum[16 + row] + ssum[32 + row] + ssum[48 + row]);
      l_run1[r] = l_run1[r] * alpha1[r] +
                  (ssum[64 + row] + ssum[80 + row] + ssum[96 + row] + ssum[112 + row]);
    }

    // --- PV: A = P (LDS), B = VT direct global; per-ct loads ---------------
    f16x8 pf00 = *(const f16x8*)&p_lds[l15 * 72 + quad * 8];
    f16x8 pf01 = *(const f16x8*)&p_lds[l15 * 72 + 32 + quad * 8];
    f16x8 pf10 = *(const f16x8*)&p_lds[(16 + l15) * 72 + quad * 8];
    f16x8 pf11 = *(const f16x8*)&p_lds[(16 + l15) * 72 + 32 + quad * 8];
    const f16* vpm = vb0 + m0 + quad * 8;
    const f16* vph = vb1 + m0 + quad * 8;
    const f16* vpl = vb2 + m0 + quad * 8;
#pragma unroll
    for (int ct = 0; ct < 4; ++ct) {
      const size_t o = (size_t)ct * (16 * 4096);
      f16x8 vm0 = *(const f16x8*)(vpm + o);
      f16x8 vm1 = *(const f16x8*)(vpm + o + 32);
      f16x8 vh0 = *(const f16x8*)(vph + o);
      f16x8 vh1 = *(const f16x8*)(vph + o + 32);
      f16x8 vl0 = *(const f16x8*)(vpl + o);
      f16x8 vl1 = *(const f16x8*)(vpl + o + 32);
      accM0[ct] = __builtin_amdgcn_mfma_f32_16x16x32_f16(pf00, vm0, accM0[ct], 0, 0, 0);
      accM0[ct] = __builtin_amdgcn_mfma_f32_16x16x32_f16(pf01, vm1, accM0[ct], 0, 0, 0);
      accM1[ct] = __builtin_amdgcn_mfma_f32_16x16x32_f16(pf10, vm0, accM1[ct], 0, 0, 0);
      accM1[ct] = __builtin_amdgcn_mfma_f32_16x16x32_f16(pf11, vm1, accM1[ct], 0, 0, 0);
      accE0[ct] = __builtin_amdgcn_mfma_f32_16x16x32_f16(pf00, vh0, accE0[ct], 0, 0, 0);
      accE0[ct] = __builtin_amdgcn_mfma_f32_16x16x32_f16(pf01, vh1, accE0[ct], 0, 0, 0);
      accE1[ct] = __builtin_amdgcn_mfma_f32_16x16x32_f16(pf10, vh0, accE1[ct], 0, 0, 0);
      accE1[ct] = __builtin_amdgcn_mfma_f32_16x16x32_f16(pf11, vh1, accE1[ct], 0, 0, 0);
      accE0[ct] = __builtin_amdgcn_mfma_f32_16x16x32_f16(pf00, vl0, accE0[ct], 0, 0, 0);
      accE0[ct] = __builtin_amdgcn_mfma_f32_16x16x32_f16(pf01, vl1, accE0[ct], 0, 0, 0);
      accE1[ct] = __builtin_amdgcn_mfma_f32_16x16x32_f16(pf10, vl0, accE1[ct], 0, 0, 0);
      accE1[ct] = __builtin_amdgcn_mfma_f32_16x16x32_f16(pf11, vl1, accE1[ct], 0, 0, 0);
    }
  }

  // ---------------- epilogue (wave-local, no LDS, no barriers) ------------
  float inv0[4], inv1[4];
#pragma unroll
  for (int r = 0; r < 4; ++r) {
    inv0[r] = 1.0f / l_run0[r];
    inv1[r] = 1.0f / l_run1[r];
  }

  const size_t base = ((size_t)b * 512) * 4096 + n0 + quad * 4;
#pragma unroll
  for (int ct = 0; ct < 4; ++ct) {
    int c = wv * 64 + ct * 16 + l15;
    size_t off0 = base + (size_t)c * 4096;
    size_t off1 = off0 + 16;
    f32x4 cxv0 = *(const f32x4*)(cx + off0);
    f32x4 cxv1 = *(const f32x4*)(cx + off1);
    f32x4 o0, o1;
#pragma unroll
    for (int r = 0; r < 4; ++r) {
      float m = accM0[ct][r] * inv0[r];
      float e2 = accE0[ct][r] * inv0[r];
      float sd = sqrtf(fmaxf(e2 - m * m, 0.f));
      o0[r] = sd * cxv0[r] + m;
      float m1 = accM1[ct][r] * inv1[r];
      float e21 = accE1[ct][r] * inv1[r];
      float sd1 = sqrtf(fmaxf(e21 - m1 * m1, 0.f));
      o1[r] = sd1 * cxv1[r] + m1;
    }
    *(f32x4*)(out + off0) = o0;
    *(f32x4*)(out + off1) = o1;
  }
}

// ---------------------------------------------------------------------------
extern "C" void kernel_launch(void* const* d_in, const int* in_sizes, int n_in,
                              void* d_out, int out_size, void* d_ws, size_t ws_size,
                              hipStream_t stream) {
  (void)in_sizes; (void)n_in; (void)out_size;
  const float* c_x  = (const float*)d_in[0];
  const float* s_x  = (const float*)d_in[1];
  const float* c_1x = (const float*)d_in[2];
  const float* s_1x = (const float*)d_in[3];
  const float* f_w  = (const float*)d_in[4];
  const float* f_b  = (const float*)d_in[5];
  const float* g_w  = (const float*)d_in[6];
  const float* g_b  = (const float*)d_in[7];
  const float* h_w  = (const float*)d_in[8];
  const float* h_b  = (const float*)d_in[9];
  float* out = (float*)d_out;

  const size_t fe = (size_t)4 * 4096 * 512;  // elements per F/G buffer
  f16* Fb = (f16*)d_ws;
  f16* Gb = Fb + fe;
  f16* VT = Gb + fe;
  const size_t need = fe * 2 * sizeof(f16) * 2 + (size_t)4 * 1536 * 4096 * sizeof(f16);
  if (ws_size < need) return;  // 80 MiB required; fail loudly (output stays poisoned)

  dim3 gP(64, 8, 4);
  conv_ik<<<gP, dim3(256), 0, stream>>>(c_1x, f_w, f_b, Fb);
  conv_ik<<<gP, dim3(256), 0, stream>>>(s_1x, g_w, g_b, Gb);
  conv_vt<<<gP, dim3(256), 0, stream>>>(s_x, h_w, h_b, VT);
  adaattn_flash<<<dim3(512), dim3(512), 0, stream>>>(Fb, Gb, VT, c_x, out);
}

// Round 8
// 1614.031 us; speedup vs baseline: 1.4040x; 1.4022x over previous
//
#include <hip/hip_runtime.h>
#include <cstdint>
#include <cstddef>

// ---------------------------------------------------------------------------
// AdaAttN fused kernel set, fp16 MFMA path.
//   B=4, C=KP=512, N=M=4096.
//   ws: Fb | Gb | VT, same byte sizes as before (16MB+16MB+48MB) but now in
//   FRAGMENT-LINEAR layouts (R11):
//     FF/GF (per batch, 2097152 f16): off = (r16*16+ks)*512 + lane*8 + j
//       holds X[i][k] with r16=i>>4, lane=(k>>3&3)*16+(i&15), ks=k>>5, j=k&7.
//     VTF (per batch, 6291456 f16):
//       off = (((mt*8+wv)*3+g)*4+ct)*2+h)*512 + lane*8 + j
//       holds group-g value for ch=wv*64+ct*16+(lane&15), m=mt*64+h*32+(lane>>4)*8+j
//       g: 0=v-hat, 1=fp16(v^2) hi, 2=lo residual (protects e2-mean^2).
//
// R11: defeat the TA gather bottleneck (single mechanism change vs R10).
//   R10 post-mortem: FETCH halved (L2-residency worked) yet time unchanged
//   -> not BW-bound anywhere. Model that fits R5/R8/R9/R10 within 15%:
//   every fragment load was a 16-scattered-line gather costing ~80 CU-cyc
//   (~5 cyc/line in TA); time = total gathers x 80 / 256 CU. Fix: producers
//   write F/G/VT in fragment-linear order so EVERY flash load is one
//   contiguous 1KB wave-load (base + lane*16B, 16 sequential lines ~1cyc/ln).
//   Same load count, ~4x cheaper each. Flash math/order bit-identical.
//   Kept: 8 waves x 64ch, 64 AGPR acc, merged e2 hi+lo, wave-local epilogue,
//   XCD-batch swizzle, launch_bounds(512,2), ~5.6KB LDS.
//   NOTE: every loop touching acc[]/m_run/l_run MUST be fully unrolled --
//   a runtime index demotes the array to scratch (R1/R2 bug).
//   Spill tripwire: WRITE_SIZE >> 40 MB per dispatch.
// ---------------------------------------------------------------------------

typedef _Float16 f16;
typedef _Float16 f16x8 __attribute__((ext_vector_type(8)));
typedef float f32x4 __attribute__((ext_vector_type(4)));

#define LOG2E 1.44269504088896340736f

// ---------------------------------------------------------------------------
// conv_ik: val[b][i][k] = bias[k] + sum_c wm[k][c] * in[b][c][i]
//   stored FRAGMENT-LINEAR (FF/GF layout above). Math identical to R10.
// ---------------------------------------------------------------------------
__global__ __launch_bounds__(256, 2) void conv_ik(
    const float* __restrict__ in, const float* __restrict__ wm,
    const float* __restrict__ bias, f16* __restrict__ out) {
  const int i0 = blockIdx.x * 64;
  const int k0 = blockIdx.y * 64;
  const int b = blockIdx.z;
  const int tid = threadIdx.x;
  const int lane = tid & 63;
  const int wv = tid >> 6;
  const int l15 = lane & 15;
  const int quad = lane >> 4;

  __shared__ __align__(16) f16 a_lds[64 * 40];  // [i][c] stride 40 (pad)

  const float* inb = in + (size_t)b * (512 * 4096);

  f32x4 acc[4];
#pragma unroll
  for (int t = 0; t < 4; ++t) acc[t] = f32x4{0.f, 0.f, 0.f, 0.f};

  for (int cs = 0; cs < 512; cs += 32) {
    __syncthreads();
#pragma unroll
    for (int rep = 0; rep < 2; ++rep) {
      int chunk = tid + rep * 256;  // 0..511
      int cc = chunk >> 4;          // 0..31
      int f4 = chunk & 15;          // 0..15
      float4 v = *(const float4*)(inb + (size_t)(cs + cc) * 4096 + i0 + f4 * 4);
      int ib = f4 * 4;
      a_lds[(ib + 0) * 40 + cc] = (f16)v.x;
      a_lds[(ib + 1) * 40 + cc] = (f16)v.y;
      a_lds[(ib + 2) * 40 + cc] = (f16)v.z;
      a_lds[(ib + 3) * 40 + cc] = (f16)v.w;
    }
    __syncthreads();
    f16x8 af = *(const f16x8*)&a_lds[(wv * 16 + l15) * 40 + quad * 8];
#pragma unroll
    for (int ct = 0; ct < 4; ++ct) {
      const float* wp = wm + (size_t)(k0 + ct * 16 + l15) * 512 + cs + quad * 8;
      float4 w0 = *(const float4*)wp;
      float4 w1 = *(const float4*)(wp + 4);
      f16x8 bf;
      bf[0] = (f16)w0.x; bf[1] = (f16)w0.y; bf[2] = (f16)w0.z; bf[3] = (f16)w0.w;
      bf[4] = (f16)w1.x; bf[5] = (f16)w1.y; bf[6] = (f16)w1.z; bf[7] = (f16)w1.w;
      acc[ct] = __builtin_amdgcn_mfma_f32_16x16x32_f16(af, bf, acc[ct], 0, 0, 0);
    }
  }
  f16* ob = out + (size_t)b * (4096 * 512);
#pragma unroll
  for (int ct = 0; ct < 4; ++ct) {
    int k = k0 + ct * 16 + l15;
    float bv = bias[k];
    int ks = k >> 5;
    int q = (k >> 3) & 3;
    int j = k & 7;
#pragma unroll
    for (int r = 0; r < 4; ++r) {
      int i = i0 + wv * 16 + quad * 4 + r;
      int r16 = i >> 4;
      int li = i & 15;
      ob[(size_t)(r16 * 16 + ks) * 512 + (q * 16 + li) * 8 + j] = (f16)(acc[ct][r] + bv);
    }
  }
}

// ---------------------------------------------------------------------------
// conv_vt: val = bias[k] + sum_c wm[k][c] * in[b][c][i]
//   stored FRAGMENT-LINEAR (VTF layout above): g=0 val, g=1 hi(val^2), g=2 lo.
// ---------------------------------------------------------------------------
__global__ __launch_bounds__(256, 2) void conv_vt(
    const float* __restrict__ in, const float* __restrict__ wm,
    const float* __restrict__ bias, f16* __restrict__ vt) {
  const int i0 = blockIdx.x * 64;
  const int k0 = blockIdx.y * 64;
  const int b = blockIdx.z;
  const int tid = threadIdx.x;
  const int lane = tid & 63;
  const int wv = tid >> 6;
  const int l15 = lane & 15;
  const int quad = lane >> 4;

  __shared__ __align__(16) f16 b_lds[64 * 40];  // [i][c] stride 40

  const float* inb = in + (size_t)b * (512 * 4096);

  f32x4 acc[4];
#pragma unroll
  for (int t = 0; t < 4; ++t) acc[t] = f32x4{0.f, 0.f, 0.f, 0.f};

  for (int cs = 0; cs < 512; cs += 32) {
    __syncthreads();
#pragma unroll
    for (int rep = 0; rep < 2; ++rep) {
      int chunk = tid + rep * 256;
      int cc = chunk >> 4;
      int f4 = chunk & 15;
      float4 v = *(const float4*)(inb + (size_t)(cs + cc) * 4096 + i0 + f4 * 4);
      int ib = f4 * 4;
      b_lds[(ib + 0) * 40 + cc] = (f16)v.x;
      b_lds[(ib + 1) * 40 + cc] = (f16)v.y;
      b_lds[(ib + 2) * 40 + cc] = (f16)v.z;
      b_lds[(ib + 3) * 40 + cc] = (f16)v.w;
    }
    __syncthreads();
    const float* wp = wm + (size_t)(k0 + wv * 16 + l15) * 512 + cs + quad * 8;
    float4 w0 = *(const float4*)wp;
    float4 w1 = *(const float4*)(wp + 4);
    f16x8 af;
    af[0] = (f16)w0.x; af[1] = (f16)w0.y; af[2] = (f16)w0.z; af[3] = (f16)w0.w;
    af[4] = (f16)w1.x; af[5] = (f16)w1.y; af[6] = (f16)w1.z; af[7] = (f16)w1.w;
#pragma unroll
    for (int ct = 0; ct < 4; ++ct) {
      f16x8 bfr = *(const f16x8*)&b_lds[(ct * 16 + l15) * 40 + quad * 8];
      acc[ct] = __builtin_amdgcn_mfma_f32_16x16x32_f16(af, bfr, acc[ct], 0, 0, 0);
    }
  }
  f16* vtb = vt + (size_t)b * 6291456;  // per-batch VTF
#pragma unroll
  for (int ct = 0; ct < 4; ++ct) {
    int i = i0 + ct * 16 + l15;
    int mt = i >> 6;
    int mi = i & 63;
    int h = mi >> 5;
    int q2 = (mi >> 3) & 3;
    int j = mi & 7;
#pragma unroll
    for (int r = 0; r < 4; ++r) {
      int k = k0 + wv * 16 + quad * 4 + r;
      float val = acc[ct][r] + bias[k];
      f16 vh = (f16)val;
      float vf = (float)vh;
      float sq = vf * vf;
      f16 sqh = (f16)sq;
      f16 sql = (f16)(sq - (float)sqh);
      int wvt = k >> 6;
      int ctt = (k >> 4) & 3;
      int l15t = k & 15;
      size_t o0 = (size_t)((mt * 8 + wvt) * 3) * 4096 +
                  (size_t)(ctt * 2 + h) * 512 + (q2 * 16 + l15t) * 8 + j;
      vtb[o0] = vh;             // g=0
      vtb[o0 + 4096] = sqh;     // g=1
      vtb[o0 + 8192] = sql;     // g=2
    }
  }
}

// ---------------------------------------------------------------------------
// adaattn_flash: per block = 32 Q-rows of one batch; 8 waves; M-tiles of 64.
//   ALL global loads are contiguous 1KB wave-loads (base + lane*16B) thanks
//   to fragment-linear FF/GF/VTF layouts. Math identical to R9/R10.
//   QK: wave w computes logit tile (rowtile rt=w>>2, colgroup cg=w&3).
//   PV: wave w owns V channels [w*64,+64): acc = 16 tiles = 64 AGPR; e2 hi
//   AND lo accumulate into the same accE (MFMA C is in/out).
//   Epilogue wave-local. LDS ~5.6KB. launch_bounds(512,2): no spill (R9).
// ---------------------------------------------------------------------------
__global__ __launch_bounds__(512, 2) void adaattn_flash(
    const f16* __restrict__ Fb, const f16* __restrict__ Gb,
    const f16* __restrict__ VT, const float* __restrict__ cx,
    float* __restrict__ out) {
  // --- XCD-batch swizzle: round-robin wgid->XCD (xcd = wg & 7, m09) --------
  const int wg = blockIdx.x;          // 0..511
  const int xcd = wg & 7;             // presumed XCD id
  const int b = xcd >> 1;             // 2 XCDs per batch
  const int n0 = (((xcd & 1) << 6) + (wg >> 3)) * 32;  // bijective: 128 slots/batch

  const int tid = threadIdx.x;
  const int lane = tid & 63;
  const int wv = tid >> 6;     // 0..7
  const int l15 = lane & 15;
  const int quad = lane >> 4;
  const int rt = wv >> 2;      // QK rowtile (0/1)
  const int cg = wv & 3;       // QK colgroup (16 cols)

  __shared__ __align__(16) f16 p_lds[32 * 72];  // [qrow 0..31][mcol] stride 72
  __shared__ float smax[128];                   // [rt][cg][row16]
  __shared__ float ssum[128];

  // fragment-linear bases (f16 units); each load below = base + lane*8 f16,
  // i.e. one contiguous 1KB per wave.
  const f16* fW = Fb + (size_t)b * 2097152 +
                  ((size_t)(n0 >> 4) + rt) * 8192 + (size_t)lane * 8;
  const f16* gW = Gb + (size_t)b * 2097152 +
                  (size_t)cg * 8192 + (size_t)lane * 8;
  const f16* vW = VT + (size_t)b * 6291456 +
                  (size_t)wv * 12288 + (size_t)lane * 8;

  f32x4 accM0[4], accE0[4], accM1[4], accE1[4];
#pragma unroll
  for (int t = 0; t < 4; ++t) {
    accM0[t] = f32x4{0.f, 0.f, 0.f, 0.f};
    accE0[t] = f32x4{0.f, 0.f, 0.f, 0.f};
    accM1[t] = f32x4{0.f, 0.f, 0.f, 0.f};
    accE1[t] = f32x4{0.f, 0.f, 0.f, 0.f};
  }
  float m_run0[4] = {-1e30f, -1e30f, -1e30f, -1e30f};
  float m_run1[4] = {-1e30f, -1e30f, -1e30f, -1e30f};
  float l_run0[4] = {0.f, 0.f, 0.f, 0.f};
  float l_run1[4] = {0.f, 0.f, 0.f, 0.f};

  for (int m0 = 0; m0 < 4096; m0 += 64) {
    // --- QK: one 16x16 logit tile per wave, K=512; 32 contiguous loads -----
    f32x4 lg = f32x4{0.f, 0.f, 0.f, 0.f};
    {
      const f16* gq = gW + (size_t)m0 * 512;  // (m0>>4)*8192
#pragma unroll 8
      for (int ks = 0; ks < 16; ++ks) {
        f16x8 gf = *(const f16x8*)(gq + ks * 512);
        f16x8 ff = *(const f16x8*)(fW + ks * 512);
        lg = __builtin_amdgcn_mfma_f32_16x16x32_f16(ff, gf, lg, 0, 0, 0);
      }
    }

    // --- wave-local row max over this wave's 16 cols (butterfly) -----------
#pragma unroll
    for (int r = 0; r < 4; ++r) {
      float v = lg[r];
      v = fmaxf(v, __shfl_xor(v, 1));
      v = fmaxf(v, __shfl_xor(v, 2));
      v = fmaxf(v, __shfl_xor(v, 4));
      v = fmaxf(v, __shfl_xor(v, 8));
      if (l15 == 0) smax[rt * 64 + cg * 16 + quad * 4 + r] = v;
    }
    __syncthreads();  // bar1: smax complete; fences prev-iter p_lds reads

    float alpha0[4], alpha1[4], ts[4];
#pragma unroll
    for (int r = 0; r < 4; ++r) {
      int row = quad * 4 + r;
      // running max for BOTH rowtiles (needed to rescale this wave's acc)
      float mt0 = fmaxf(fmaxf(smax[row], smax[16 + row]),
                        fmaxf(smax[32 + row], smax[48 + row]));
      float mt1 = fmaxf(fmaxf(smax[64 + row], smax[80 + row]),
                        fmaxf(smax[96 + row], smax[112 + row]));
      float mn0 = fmaxf(m_run0[r], mt0);
      float mn1 = fmaxf(m_run1[r], mt1);
      alpha0[r] = exp2f((m_run0[r] - mn0) * LOG2E);
      alpha1[r] = exp2f((m_run1[r] - mn1) * LOG2E);
      m_run0[r] = mn0;
      m_run1[r] = mn1;
      // P for this wave's OWN logit tile (rt is wave-uniform)
      float mn_my = rt ? mn1 : mn0;
      float p = exp2f((lg[r] - mn_my) * LOG2E);
      f16 ph = (f16)p;  // round first so weights & sums agree exactly
      p = (float)ph;
      p_lds[(rt * 16 + row) * 72 + cg * 16 + l15] = ph;
      float s = p;
      s += __shfl_xor(s, 1);
      s += __shfl_xor(s, 2);
      s += __shfl_xor(s, 4);
      s += __shfl_xor(s, 8);
      ts[r] = s;
    }
    if (l15 == 0) {
#pragma unroll
      for (int r = 0; r < 4; ++r) ssum[rt * 64 + cg * 16 + quad * 4 + r] = ts[r];
    }
    // rescale accumulators by alpha (per-row); skip when all alpha == 1
    if (__any(alpha0[0] != 1.f || alpha0[1] != 1.f ||
              alpha0[2] != 1.f || alpha0[3] != 1.f ||
              alpha1[0] != 1.f || alpha1[1] != 1.f ||
              alpha1[2] != 1.f || alpha1[3] != 1.f)) {
#pragma unroll
      for (int t = 0; t < 4; ++t) {
#pragma unroll
        for (int r = 0; r < 4; ++r) {
          accM0[t][r] *= alpha0[r];
          accE0[t][r] *= alpha0[r];
          accM1[t][r] *= alpha1[r];
          accE1[t][r] *= alpha1[r];
        }
      }
    }
    __syncthreads();  // bar2: p_lds + ssum complete

#pragma unroll
    for (int r = 0; r < 4; ++r) {
      int row = quad * 4 + r;
      l_run0[r] = l_run0[r] * alpha0[r] +
                  (ssum[row] + ssum[16 + row] + ssum[32 + row] + ssum[48 + row]);
      l_run1[r] = l_run1[r] * alpha1[r] +
                  (ssum[64 + row] + ssum[80 + row] + ssum[96 + row] + ssum[112 + row]);
    }

    // --- PV: A = P (LDS), B = VTF contiguous 1KB loads; per-ct loads -------
    f16x8 pf00 = *(const f16x8*)&p_lds[l15 * 72 + quad * 8];
    f16x8 pf01 = *(const f16x8*)&p_lds[l15 * 72 + 32 + quad * 8];
    f16x8 pf10 = *(const f16x8*)&p_lds[(16 + l15) * 72 + quad * 8];
    f16x8 pf11 = *(const f16x8*)&p_lds[(16 + l15) * 72 + 32 + quad * 8];
    const f16* vti = vW + (size_t)(m0 >> 6) * 98304;  // 8 waves * 3g * 4ct * 2h * 512
#pragma unroll
    for (int ct = 0; ct < 4; ++ct) {
      f16x8 vm0 = *(const f16x8*)(vti + ct * 1024);
      f16x8 vm1 = *(const f16x8*)(vti + ct * 1024 + 512);
      f16x8 vh0 = *(const f16x8*)(vti + 4096 + ct * 1024);
      f16x8 vh1 = *(const f16x8*)(vti + 4096 + ct * 1024 + 512);
      f16x8 vl0 = *(const f16x8*)(vti + 8192 + ct * 1024);
      f16x8 vl1 = *(const f16x8*)(vti + 8192 + ct * 1024 + 512);
      accM0[ct] = __builtin_amdgcn_mfma_f32_16x16x32_f16(pf00, vm0, accM0[ct], 0, 0, 0);
      accM0[ct] = __builtin_amdgcn_mfma_f32_16x16x32_f16(pf01, vm1, accM0[ct], 0, 0, 0);
      accM1[ct] = __builtin_amdgcn_mfma_f32_16x16x32_f16(pf10, vm0, accM1[ct], 0, 0, 0);
      accM1[ct] = __builtin_amdgcn_mfma_f32_16x16x32_f16(pf11, vm1, accM1[ct], 0, 0, 0);
      accE0[ct] = __builtin_amdgcn_mfma_f32_16x16x32_f16(pf00, vh0, accE0[ct], 0, 0, 0);
      accE0[ct] = __builtin_amdgcn_mfma_f32_16x16x32_f16(pf01, vh1, accE0[ct], 0, 0, 0);
      accE1[ct] = __builtin_amdgcn_mfma_f32_16x16x32_f16(pf10, vh0, accE1[ct], 0, 0, 0);
      accE1[ct] = __builtin_amdgcn_mfma_f32_16x16x32_f16(pf11, vh1, accE1[ct], 0, 0, 0);
      accE0[ct] = __builtin_amdgcn_mfma_f32_16x16x32_f16(pf00, vl0, accE0[ct], 0, 0, 0);
      accE0[ct] = __builtin_amdgcn_mfma_f32_16x16x32_f16(pf01, vl1, accE0[ct], 0, 0, 0);
      accE1[ct] = __builtin_amdgcn_mfma_f32_16x16x32_f16(pf10, vl0, accE1[ct], 0, 0, 0);
      accE1[ct] = __builtin_amdgcn_mfma_f32_16x16x32_f16(pf11, vl1, accE1[ct], 0, 0, 0);
    }
  }

  // ---------------- epilogue (wave-local, no LDS, no barriers) ------------
  float inv0[4], inv1[4];
#pragma unroll
  for (int r = 0; r < 4; ++r) {
    inv0[r] = 1.0f / l_run0[r];
    inv1[r] = 1.0f / l_run1[r];
  }

  const size_t base = ((size_t)b * 512) * 4096 + n0 + quad * 4;
#pragma unroll
  for (int ct = 0; ct < 4; ++ct) {
    int c = wv * 64 + ct * 16 + l15;
    size_t off0 = base + (size_t)c * 4096;
    size_t off1 = off0 + 16;
    f32x4 cxv0 = *(const f32x4*)(cx + off0);
    f32x4 cxv1 = *(const f32x4*)(cx + off1);
    f32x4 o0, o1;
#pragma unroll
    for (int r = 0; r < 4; ++r) {
      float m = accM0[ct][r] * inv0[r];
      float e2 = accE0[ct][r] * inv0[r];
      float sd = sqrtf(fmaxf(e2 - m * m, 0.f));
      o0[r] = sd * cxv0[r] + m;
      float m1 = accM1[ct][r] * inv1[r];
      float e21 = accE1[ct][r] * inv1[r];
      float sd1 = sqrtf(fmaxf(e21 - m1 * m1, 0.f));
      o1[r] = sd1 * cxv1[r] + m1;
    }
    *(f32x4*)(out + off0) = o0;
    *(f32x4*)(out + off1) = o1;
  }
}

// ---------------------------------------------------------------------------
extern "C" void kernel_launch(void* const* d_in, const int* in_sizes, int n_in,
                              void* d_out, int out_size, void* d_ws, size_t ws_size,
                              hipStream_t stream) {
  (void)in_sizes; (void)n_in; (void)out_size;
  const float* c_x  = (const float*)d_in[0];
  const float* s_x  = (const float*)d_in[1];
  const float* c_1x = (const float*)d_in[2];
  const float* s_1x = (const float*)d_in[3];
  const float* f_w  = (const float*)d_in[4];
  const float* f_b  = (const float*)d_in[5];
  const float* g_w  = (const float*)d_in[6];
  const float* g_b  = (const float*)d_in[7];
  const float* h_w  = (const float*)d_in[8];
  const float* h_b  = (const float*)d_in[9];
  float* out = (float*)d_out;

  const size_t fe = (size_t)4 * 4096 * 512;  // elements per F/G buffer
  f16* Fb = (f16*)d_ws;
  f16* Gb = Fb + fe;
  f16* VT = Gb + fe;
  const size_t need = fe * 2 * sizeof(f16) * 2 + (size_t)4 * 1536 * 4096 * sizeof(f16);
  if (ws_size < need) return;  // 80 MiB required; fail loudly (output stays poisoned)

  dim3 gP(64, 8, 4);
  conv_ik<<<gP, dim3(256), 0, stream>>>(c_1x, f_w, f_b, Fb);
  conv_ik<<<gP, dim3(256), 0, stream>>>(s_1x, g_w, g_b, Gb);
  conv_vt<<<gP, dim3(256), 0, stream>>>(s_x, h_w, h_b, VT);
  adaattn_flash<<<dim3(512), dim3(512), 0, stream>>>(Fb, Gb, VT, c_x, out);
}